// Round 1
// baseline (360.151 us; speedup 1.0000x reference)
//
#include <hip/hip_runtime.h>
#include <math.h>

#define LMAX 8

// Host-computed coefficient pack, passed by value as a kernel arg (972 B < 4 KB).
// F[l][m] for m>=1: (-1)^m * sqrt((2l+1)/(2pi) * (l-m)!/(l+m)!)
// F[l][0]:          sqrt((2l+1)/(4pi))
// A[l][m] = (2l-1)/(l-m), B[l][m] = (l+m-1)/(l-m)  (recurrence with division folded in)
struct Coefs {
    float F[LMAX + 1][LMAX + 1];
    float A[LMAX + 1][LMAX + 1];
    float B[LMAX + 1][LMAX + 1];
};

__global__ __launch_bounds__(256) void solid_harmonics_kernel(
    const float* __restrict__ R, float* __restrict__ out, int N, Coefs cf)
{
    int i = blockIdx.x * blockDim.x + threadIdx.x;
    if (i >= N) return;

    float x = R[3 * i + 0];
    float y = R[3 * i + 1];
    float z = R[3 * i + 2];
    float r2 = x * x + y * y + z * z;

    // c[m] + i s[m] = (x + i y)^m
    float c[LMAX + 1], s[LMAX + 1];
    c[0] = 1.0f; s[0] = 0.0f;
#pragma unroll
    for (int m = 1; m <= LMAX; ++m) {
        c[m] = x * c[m - 1] - y * s[m - 1];
        s[m] = x * s[m - 1] + y * c[m - 1];
    }

    // Q[l][m] recurrence (fully unrolled; diagonal terms constant-fold)
    float Q[LMAX + 1][LMAX + 1];
    Q[0][0] = 1.0f;
#pragma unroll
    for (int l = 1; l <= LMAX; ++l) {
        Q[l][l]     = -(2.0f * l - 1.0f) * Q[l - 1][l - 1];
        Q[l][l - 1] =  (2.0f * l - 1.0f) * z * Q[l - 1][l - 1];
#pragma unroll
        for (int m = l - 2; m >= 0; --m) {
            Q[l][m] = cf.A[l][m] * z * Q[l - 1][m] - cf.B[l][m] * r2 * Q[l - 2][m];
        }
    }

    // Output: array l lives at offset N*l*l, row-major [N, 2l+1].
    // Columns: m = l..1 -> F*Q*s[m]; col l -> F0*Q[l][0]; m = 1..l -> F*Q*c[m].
#pragma unroll
    for (int l = 0; l <= LMAX; ++l) {
        float* o = out + (size_t)N * (size_t)(l * l) + (size_t)i * (size_t)(2 * l + 1);
#pragma unroll
        for (int m = l; m >= 1; --m) {
            o[l - m] = cf.F[l][m] * Q[l][m] * s[m];
        }
        o[l] = cf.F[l][0] * Q[l][0];
#pragma unroll
        for (int m = 1; m <= l; ++m) {
            o[l + m] = cf.F[l][m] * Q[l][m] * c[m];
        }
    }
}

extern "C" void kernel_launch(void* const* d_in, const int* in_sizes, int n_in,
                              void* d_out, int out_size, void* d_ws, size_t ws_size,
                              hipStream_t stream) {
    const float* R = (const float*)d_in[0];
    float* out = (float*)d_out;
    const int N = in_sizes[0] / 3;

    // Build coefficient pack in double, cast to float.
    Coefs cf;
    double fact[2 * LMAX + 1];
    fact[0] = 1.0;
    for (int k = 1; k <= 2 * LMAX; ++k) fact[k] = fact[k - 1] * (double)k;
    const double PI = 3.14159265358979323846;
    for (int l = 0; l <= LMAX; ++l) {
        cf.F[l][0] = (float)sqrt((2.0 * l + 1.0) / (4.0 * PI));
        for (int m = 1; m <= l; ++m) {
            double sign = (m & 1) ? -1.0 : 1.0;
            cf.F[l][m] = (float)(sign * sqrt((2.0 * l + 1.0) / (2.0 * PI)
                                             * fact[l - m] / fact[l + m]));
        }
        for (int m = 0; m <= l - 2; ++m) {
            cf.A[l][m] = (float)((2.0 * l - 1.0) / (double)(l - m));
            cf.B[l][m] = (float)((double)(l + m - 1) / (double)(l - m));
        }
    }
    // Zero unused slots (deterministic arg bytes for graph capture).
    for (int l = 0; l <= LMAX; ++l)
        for (int m = 0; m <= LMAX; ++m) {
            if (m > l) { cf.F[l][m] = 0.f; }
            if (m > l - 2) { cf.A[l][m] = 0.f; cf.B[l][m] = 0.f; }
        }

    const int block = 256;
    const int grid = (N + block - 1) / block;
    solid_harmonics_kernel<<<grid, block, 0, stream>>>(R, out, N, cf);
}

// Round 2
// 328.443 us; speedup vs baseline: 1.0965x; 1.0965x over previous
//
#include <hip/hip_runtime.h>
#include <math.h>
#include <stdint.h>

#define LMAX 8
#define NPB 256  // points per block

// Host-computed coefficient pack, passed by value as a kernel arg.
// F[l][m] for m>=1: (-1)^m * sqrt((2l+1)/(2pi) * (l-m)!/(l+m)!)
// F[l][0]:          sqrt((2l+1)/(4pi))
// A[l][m] = (2l-1)/(l-m), B[l][m] = (l+m-1)/(l-m)
struct Coefs {
    float F[LMAX + 1][LMAX + 1];
    float A[LMAX + 1][LMAX + 1];
    float B[LMAX + 1][LMAX + 1];
};

__global__ __launch_bounds__(256) void solid_harmonics_kernel(
    const float* __restrict__ R, float* __restrict__ out, int N, Coefs cf)
{
    // Tile for one l at a time: 256 rows x (2l+1) cols, max 256*17 floats = 17.4 KB.
    __shared__ __align__(16) float tile[NPB * (2 * LMAX + 1)];

    const int t = threadIdx.x;
    const int i0 = blockIdx.x * NPB;
    const int i = i0 + t;
    const int rows = min(NPB, N - i0);
    const bool valid = (i < N);

    float x = 0.f, y = 0.f, z = 0.f;
    if (valid) {
        x = R[3 * i + 0];
        y = R[3 * i + 1];
        z = R[3 * i + 2];
    }
    const float r2 = x * x + y * y + z * z;

    // c[m] + i s[m] = (x+iy)^m, built incrementally.
    float c[LMAX + 1], s[LMAX + 1];
    c[0] = 1.f; s[0] = 0.f;

    // Rolling Q rows: Qcur = row l, Qm1 = row l-1, Qm2 = row l-2.
    float Qcur[LMAX + 1], Qm1[LMAX + 1], Qm2[LMAX + 1];
    Qcur[0] = 1.f;

#pragma unroll
    for (int l = 0; l <= LMAX; ++l) {
        if (l >= 1) {
            // shift rows (register renames after full unroll)
#pragma unroll
            for (int m = 0; m < l - 1; ++m) Qm2[m] = Qm1[m];
#pragma unroll
            for (int m = 0; m < l; ++m) Qm1[m] = Qcur[m];
            c[l] = x * c[l - 1] - y * s[l - 1];
            s[l] = x * s[l - 1] + y * c[l - 1];
            Qcur[l]     = -(2.f * l - 1.f) * Qm1[l - 1];
            Qcur[l - 1] =  (2.f * l - 1.f) * z * Qm1[l - 1];
#pragma unroll
            for (int m = l - 2; m >= 0; --m)
                Qcur[m] = cf.A[l][m] * z * Qm1[m] - cf.B[l][m] * r2 * Qm2[m];
        }

        const int stride = 2 * l + 1;

        // Stage this point's row into LDS. Odd stride -> <=2-way bank aliasing (free).
        {
            float* row = &tile[t * stride];
#pragma unroll
            for (int m = l; m >= 1; --m) row[l - m] = cf.F[l][m] * Qcur[m] * s[m];
            row[l] = cf.F[l][0] * Qcur[0];
#pragma unroll
            for (int m = 1; m <= l; ++m) row[l + m] = cf.F[l][m] * Qcur[m] * c[m];
        }
        __syncthreads();

        // Cooperative coalesced copy-out of the block's contiguous region for this l.
        {
            float* obase = out + (size_t)N * (size_t)(l * l) + (size_t)i0 * (size_t)stride;
            const int E = rows * stride;
            if ((((uintptr_t)obase) & 15u) == 0) {
                const int E4 = E >> 2;  // float4 count
                const float4* t4 = (const float4*)tile;
                float4* o4 = (float4*)obase;
                for (int e = t; e < E4; e += NPB) o4[e] = t4[e];
                for (int e = (E4 << 2) + t; e < E; e += NPB) obase[e] = tile[e];
            } else {
                for (int e = t; e < E; e += NPB) obase[e] = tile[e];
            }
        }
        __syncthreads();  // tile reused next l
    }
}

extern "C" void kernel_launch(void* const* d_in, const int* in_sizes, int n_in,
                              void* d_out, int out_size, void* d_ws, size_t ws_size,
                              hipStream_t stream) {
    const float* R = (const float*)d_in[0];
    float* out = (float*)d_out;
    const int N = in_sizes[0] / 3;

    Coefs cf;
    double fact[2 * LMAX + 1];
    fact[0] = 1.0;
    for (int k = 1; k <= 2 * LMAX; ++k) fact[k] = fact[k - 1] * (double)k;
    const double PI = 3.14159265358979323846;
    for (int l = 0; l <= LMAX; ++l) {
        for (int m = 0; m <= LMAX; ++m) { cf.F[l][m] = 0.f; cf.A[l][m] = 0.f; cf.B[l][m] = 0.f; }
        cf.F[l][0] = (float)sqrt((2.0 * l + 1.0) / (4.0 * PI));
        for (int m = 1; m <= l; ++m) {
            double sign = (m & 1) ? -1.0 : 1.0;
            cf.F[l][m] = (float)(sign * sqrt((2.0 * l + 1.0) / (2.0 * PI)
                                             * fact[l - m] / fact[l + m]));
        }
        for (int m = 0; m <= l - 2; ++m) {
            cf.A[l][m] = (float)((2.0 * l - 1.0) / (double)(l - m));
            cf.B[l][m] = (float)((double)(l + m - 1) / (double)(l - m));
        }
    }

    const int block = NPB;
    const int grid = (N + block - 1) / block;
    solid_harmonics_kernel<<<grid, block, 0, stream>>>(R, out, N, cf);
}

// Round 3
// 327.410 us; speedup vs baseline: 1.1000x; 1.0032x over previous
//
#include <hip/hip_runtime.h>
#include <math.h>
#include <stdint.h>

#define LMAX 8
#define NPB 128  // points per block (1 thread per point, 128 threads)
#define NCOLS 81 // sum of (2l+1), l=0..8

// Host-computed coefficient pack, passed by value as a kernel arg.
// F[l][m] for m>=1: (-1)^m * sqrt((2l+1)/(2pi) * (l-m)!/(l+m)!)
// F[l][0]:          sqrt((2l+1)/(4pi))
// A[l][m] = (2l-1)/(l-m), B[l][m] = (l+m-1)/(l-m)
struct Coefs {
    float F[LMAX + 1][LMAX + 1];
    float A[LMAX + 1][LMAX + 1];
    float B[LMAX + 1][LMAX + 1];
};

// Single-barrier structure: each thread computes its point's 81 values and
// writes them into per-l LDS regions (no inter-thread sharing -> no barrier
// needed during compute). ONE __syncthreads, then a cooperative float4
// copy-out of 9 contiguous regions, with NO trailing barrier -- the stores
// drain at kernel end for free. This removes the 18 per-block barrier
// vmcnt(0) drains that serialized R2.
__global__ __launch_bounds__(NPB) void solid_harmonics_kernel(
    const float* __restrict__ R, float* __restrict__ out, int N, Coefs cf)
{
    // Region l at LDS offset NPB*l*l, row-major [NPB, 2l+1]. Total 128*81*4 = 41472 B.
    __shared__ __align__(16) float tile[NPB * NCOLS];

    const int t = threadIdx.x;
    const int i0 = blockIdx.x * NPB;
    const int i = i0 + t;
    const int rows = min(NPB, N - i0);

    float x = 0.f, y = 0.f, z = 0.f;
    if (i < N) {
        x = R[3 * i + 0];
        y = R[3 * i + 1];
        z = R[3 * i + 2];
    }
    const float r2 = x * x + y * y + z * z;

    // c[m] + i s[m] = (x+iy)^m, built incrementally.
    float c[LMAX + 1], s[LMAX + 1];
    c[0] = 1.f; s[0] = 0.f;

    // Rolling Q rows: Qcur = row l, Qm1 = row l-1, Qm2 = row l-2.
    float Qcur[LMAX + 1], Qm1[LMAX + 1], Qm2[LMAX + 1];
    Qcur[0] = 1.f;

#pragma unroll
    for (int l = 0; l <= LMAX; ++l) {
        if (l >= 1) {
#pragma unroll
            for (int m = 0; m < l - 1; ++m) Qm2[m] = Qm1[m];
#pragma unroll
            for (int m = 0; m < l; ++m) Qm1[m] = Qcur[m];
            c[l] = x * c[l - 1] - y * s[l - 1];
            s[l] = x * s[l - 1] + y * c[l - 1];
            Qcur[l]     = -(2.f * l - 1.f) * Qm1[l - 1];
            Qcur[l - 1] =  (2.f * l - 1.f) * z * Qm1[l - 1];
#pragma unroll
            for (int m = l - 2; m >= 0; --m)
                Qcur[m] = cf.A[l][m] * z * Qm1[m] - cf.B[l][m] * r2 * Qm2[m];
        }
        // Stage this point's row for this l. Odd stride -> <=2-way bank alias (free).
        float* row = &tile[NPB * l * l + t * (2 * l + 1)];
#pragma unroll
        for (int m = l; m >= 1; --m) row[l - m] = cf.F[l][m] * Qcur[m] * s[m];
        row[l] = cf.F[l][0] * Qcur[0];
#pragma unroll
        for (int m = 1; m <= l; ++m) row[l + m] = cf.F[l][m] * Qcur[m] * c[m];
    }

    __syncthreads();  // the ONLY barrier

    // Cooperative coalesced copy-out: 9 contiguous spans.
    // Full blocks: E = 128*(2l+1) divisible by 4; base 16B-aligned when
    // N % 4 == 0 (N=1e6) since i0*(2l+1) is a multiple of 128.
#pragma unroll
    for (int l = 0; l <= LMAX; ++l) {
        const int stride = 2 * l + 1;
        const float* src = &tile[NPB * l * l];
        float* obase = out + (size_t)N * (size_t)(l * l) + (size_t)i0 * (size_t)stride;
        const int E = rows * stride;
        if (((((uintptr_t)obase) & 15u) == 0) && rows == NPB) {
            const int E4 = E >> 2;
            const float4* s4 = (const float4*)src;
            float4* o4 = (float4*)obase;
            for (int e = t; e < E4; e += NPB) o4[e] = s4[e];
        } else {
            for (int e = t; e < E; e += NPB) obase[e] = src[e];
        }
    }
}

extern "C" void kernel_launch(void* const* d_in, const int* in_sizes, int n_in,
                              void* d_out, int out_size, void* d_ws, size_t ws_size,
                              hipStream_t stream) {
    const float* R = (const float*)d_in[0];
    float* out = (float*)d_out;
    const int N = in_sizes[0] / 3;

    Coefs cf;
    double fact[2 * LMAX + 1];
    fact[0] = 1.0;
    for (int k = 1; k <= 2 * LMAX; ++k) fact[k] = fact[k - 1] * (double)k;
    const double PI = 3.14159265358979323846;
    for (int l = 0; l <= LMAX; ++l) {
        for (int m = 0; m <= LMAX; ++m) { cf.F[l][m] = 0.f; cf.A[l][m] = 0.f; cf.B[l][m] = 0.f; }
        cf.F[l][0] = (float)sqrt((2.0 * l + 1.0) / (4.0 * PI));
        for (int m = 1; m <= l; ++m) {
            double sign = (m & 1) ? -1.0 : 1.0;
            cf.F[l][m] = (float)(sign * sqrt((2.0 * l + 1.0) / (2.0 * PI)
                                             * fact[l - m] / fact[l + m]));
        }
        for (int m = 0; m <= l - 2; ++m) {
            cf.A[l][m] = (float)((2.0 * l - 1.0) / (double)(l - m));
            cf.B[l][m] = (float)((double)(l + m - 1) / (double)(l - m));
        }
    }

    const int grid = (N + NPB - 1) / NPB;
    solid_harmonics_kernel<<<grid, NPB, 0, stream>>>(R, out, N, cf);
}